// Round 2
// baseline (108.995 us; speedup 1.0000x reference)
//
#include <hip/hip_runtime.h>
#include <hip/hip_cooperative_groups.h>

namespace cg = cooperative_groups;

// Problem constants (match reference file)
#define Bn  4
#define Cn  3
#define Hn  224
#define Wn  224
#define Kn  196
#define En  768
#define HW  (Hn * Wn)            // 50176 pixels per (b,c) plane
#define BPB 49                   // pooling blocks per batch
#define NPOOL (Bn * BPB)         // 196 blocks total
#define KC  (Kn * Cn)            // 588 histogram slots

// Single cooperative kernel, 196 blocks x 256 threads (co-resident: 196 <= 256 CUs,
// 9.4 KB LDS, low VGPR). Phase 1 = segmented partial sums (quad-privatized LDS
// histograms, one per wave, transposed store). grid.sync(). Phase 2 = per-wave
// reduction over the 49 partials + GEMV row: out[b,k,e] = pooled_c W[c,e] + b[e].
// Fusing kills the kernel-drain + second-launch gap between two ~3 us kernels.
__global__ __launch_bounds__(256) void fused_seg_embed(
    const float* __restrict__ img,        // (B,C,H,W)
    const int*   __restrict__ seg,        // (B,H,W)
    const float* __restrict__ Wm,         // (C,E)
    const float* __restrict__ bias,       // (E,)
    float*       __restrict__ out,        // (B,K,E)
    float*       __restrict__ partialsT)  // (B, KC, BPB) workspace, fully overwritten
{
    __shared__ float acc[4][KC];          // one histogram per wave: 9408 B
    const int tid  = threadIdx.x;
    const int lane = tid & 63;
    const int wv   = tid >> 6;

    for (int i = tid; i < 4 * KC; i += 256) ((float*)acc)[i] = 0.0f;
    __syncthreads();

    // ---------------- Phase 1: segmented partial sums ----------------
    {
        const int batch = blockIdx.x / BPB;
        const int blk   = blockIdx.x % BPB;
        const int p4    = blk * 256 + tid;   // float4 index within a plane

        const int4*   seg4 = (const int4*)(seg + (size_t)batch * HW);
        const float4* im   = (const float4*)(img + (size_t)batch * Cn * HW);

        const int4   s  = seg4[p4];
        const float4 v0 = im[p4];                 // c = 0 plane
        const float4 v1 = im[HW / 4 + p4];        // c = 1 plane
        const float4 v2 = im[2 * (HW / 4) + p4];  // c = 2 plane

        float* a = acc[wv];                  // wave-private histogram
        atomicAdd(&a[s.x * 3 + 0], v0.x);
        atomicAdd(&a[s.x * 3 + 1], v1.x);
        atomicAdd(&a[s.x * 3 + 2], v2.x);
        atomicAdd(&a[s.y * 3 + 0], v0.y);
        atomicAdd(&a[s.y * 3 + 1], v1.y);
        atomicAdd(&a[s.y * 3 + 2], v2.y);
        atomicAdd(&a[s.z * 3 + 0], v0.z);
        atomicAdd(&a[s.z * 3 + 1], v1.z);
        atomicAdd(&a[s.z * 3 + 2], v2.z);
        atomicAdd(&a[s.w * 3 + 0], v0.w);
        atomicAdd(&a[s.w * 3 + 1], v1.w);
        atomicAdd(&a[s.w * 3 + 2], v2.w);
        __syncthreads();

        // Transposed store: column j=blk of the (KC x BPB) matrix for this batch.
        // Scattered 4B stores are fire-and-forget; buys phase 2 contiguous reads.
        float* dst = partialsT + (size_t)batch * KC * BPB + blk;
        for (int sidx = tid; sidx < KC; sidx += 256)
            dst[(size_t)sidx * BPB] =
                acc[0][sidx] + acc[1][sidx] + acc[2][sidx] + acc[3][sidx];
    }

    // Make all partials visible device-wide, then proceed.
    cg::this_grid().sync();

    // ---------------- Phase 2: reduce 49 partials + embed ----------------
    {
        const int b = blockIdx.x / BPB;
        const int k = (blockIdx.x % BPB) * 4 + wv;   // each wave owns one (b,k)

        // Rows s = k*3 .. k*3+2 are contiguous: 147 floats.
        const float* row = partialsT + ((size_t)b * KC + k * 3) * BPB;
        float a0 = (lane < BPB) ? row[lane]           : 0.0f;
        float a1 = (lane < BPB) ? row[BPB + lane]     : 0.0f;
        float a2 = (lane < BPB) ? row[2 * BPB + lane] : 0.0f;

        #pragma unroll
        for (int off = 32; off > 0; off >>= 1) {
            a0 += __shfl_xor(a0, off, 64);
            a1 += __shfl_xor(a1, off, 64);
            a2 += __shfl_xor(a2, off, 64);
        }
        const float p0 = a0 * (1.0f / (float)HW);
        const float p1 = a1 * (1.0f / (float)HW);
        const float p2 = a2 * (1.0f / (float)HW);

        const float4* W4 = (const float4*)Wm;    // row c starts at c*192 float4s
        const float4* B4 = (const float4*)bias;
        float4* O4 = (float4*)out + ((size_t)b * Kn + k) * (En / 4);

        #pragma unroll
        for (int part = 0; part < 3; ++part) {
            const int idx = part * 64 + lane;    // coalesced across the wave
            const float4 w0 = W4[idx];
            const float4 w1 = W4[192 + idx];
            const float4 w2 = W4[384 + idx];
            const float4 bb = B4[idx];
            float4 r;
            r.x = p0 * w0.x + p1 * w1.x + p2 * w2.x + bb.x;
            r.y = p0 * w0.y + p1 * w1.y + p2 * w2.y + bb.y;
            r.z = p0 * w0.z + p1 * w1.z + p2 * w2.z + bb.z;
            r.w = p0 * w0.w + p1 * w1.w + p2 * w2.w + bb.w;
            O4[idx] = r;
        }
    }
}

extern "C" void kernel_launch(void* const* d_in, const int* in_sizes, int n_in,
                              void* d_out, int out_size, void* d_ws, size_t ws_size,
                              hipStream_t stream) {
    const float* img  = (const float*)d_in[0];  // (4,3,224,224) fp32
    const int*   seg  = (const int*)  d_in[1];  // (4,224,224) int32
    const float* Wm   = (const float*)d_in[2];  // (3,768) fp32
    const float* bias = (const float*)d_in[3];  // (768,) fp32
    float* out       = (float*)d_out;           // (4,196,768) fp32
    float* partialsT = (float*)d_ws;            // (B,KC,BPB) = 461 KB, fully overwritten

    void* args[] = {(void*)&img, (void*)&seg, (void*)&Wm, (void*)&bias,
                    (void*)&out, (void*)&partialsT};
    hipLaunchCooperativeKernel((const void*)fused_seg_embed,
                               dim3(NPOOL), dim3(256), args, 0, stream);
}

// Round 3
// 84.168 us; speedup vs baseline: 1.2950x; 1.2950x over previous
//
#include <hip/hip_runtime.h>

// Problem constants (match reference file)
#define Bn  4
#define Cn  3
#define Hn  224
#define Wn  224
#define Kn  196
#define En  768
#define HW  (Hn * Wn)            // 50176 pixels per (b,c) plane
#define BPB 49                   // pooling blocks per batch
#define NPOOL (Bn * BPB)         // 196 blocks total
#define KC  (Kn * Cn)            // 588 histogram slots

// Monotonic per-batch arrival counters. Module-lifetime device globals:
// zero-initialized at module load, NEVER reset. Each iteration adds exactly
// BPB per batch (stream-serialized), so a block's completion target is
// old - old%BPB + BPB. This keeps the barrier state out of the poisoned
// workspace and needs no zeroing dispatch.
__device__ unsigned int g_cnt[Bn];

// Single REGULAR launch (graph-capturable — cooperative launch measured +42us
// host overhead on this harness). Phase 1: per-block segmented partial sums
// (dual wave-pair-private LDS histograms, transposed store). Per-batch
// software barrier (CG grid-sync protocol: release fence + atomic arrive,
// spin + acquire fence). Phase 2: per-wave reduction over 49 partials + GEMV:
// out[b,k,e] = (1/HW) * sum_c pooled_c * W[c,e] + bias[e].
__global__ __launch_bounds__(256) void fused_seg_embed(
    const float* __restrict__ img,        // (B,C,H,W)
    const int*   __restrict__ seg,        // (B,H,W)
    const float* __restrict__ Wm,         // (C,E)
    const float* __restrict__ bias,       // (E,)
    float*       __restrict__ out,        // (B,K,E)
    float*       __restrict__ partialsT)  // (B, KC, BPB) workspace, fully overwritten
{
    __shared__ float acc[2][KC];          // 4704 B
    const int tid  = threadIdx.x;
    const int lane = tid & 63;
    const int wv   = tid >> 6;

    for (int i = tid; i < 2 * KC; i += 256) ((float*)acc)[i] = 0.0f;
    __syncthreads();

    const int batch = blockIdx.x / BPB;
    const int blk   = blockIdx.x % BPB;

    // ---------------- Phase 1: segmented partial sums ----------------
    {
        const int p4 = blk * 256 + tid;      // float4 index within a plane
        const int h  = tid >> 7;             // waves 0-1 -> acc[0], 2-3 -> acc[1]

        const int4*   seg4 = (const int4*)(seg + (size_t)batch * HW);
        const float4* im   = (const float4*)(img + (size_t)batch * Cn * HW);

        const int4   s  = seg4[p4];
        const float4 v0 = im[p4];                 // c = 0 plane
        const float4 v1 = im[HW / 4 + p4];        // c = 1 plane
        const float4 v2 = im[2 * (HW / 4) + p4];  // c = 2 plane

        float* a = acc[h];
        atomicAdd(&a[s.x * 3 + 0], v0.x);
        atomicAdd(&a[s.x * 3 + 1], v1.x);
        atomicAdd(&a[s.x * 3 + 2], v2.x);
        atomicAdd(&a[s.y * 3 + 0], v0.y);
        atomicAdd(&a[s.y * 3 + 1], v1.y);
        atomicAdd(&a[s.y * 3 + 2], v2.y);
        atomicAdd(&a[s.z * 3 + 0], v0.z);
        atomicAdd(&a[s.z * 3 + 1], v1.z);
        atomicAdd(&a[s.z * 3 + 2], v2.z);
        atomicAdd(&a[s.w * 3 + 0], v0.w);
        atomicAdd(&a[s.w * 3 + 1], v1.w);
        atomicAdd(&a[s.w * 3 + 2], v2.w);
        __syncthreads();

        // Transposed store: column j=blk of the (KC x BPB) matrix for batch.
        float* dst = partialsT + (size_t)batch * KC * BPB + blk;
        for (int sidx = tid; sidx < KC; sidx += 256)
            dst[(size_t)sidx * BPB] = acc[0][sidx] + acc[1][sidx];
    }

    // ---------------- Per-batch software barrier ----------------
    // __syncthreads drains every wave's global stores (compiler emits
    // s_waitcnt vmcnt(0) before s_barrier), so tid 0's release fence
    // covers the whole block's writes (all on this CU -> this XCD's L2).
    __syncthreads();
    if (tid == 0) {
        __threadfence();                               // release (L2 writeback)
        unsigned old    = atomicAdd(&g_cnt[batch], 1u);
        unsigned target = old - (old % BPB) + BPB;     // this iteration's 49th arrival
        while (__hip_atomic_load(&g_cnt[batch], __ATOMIC_RELAXED,
                                 __HIP_MEMORY_SCOPE_AGENT) < target)
            __builtin_amdgcn_s_sleep(2);
        __threadfence();                               // acquire (invalidate stale)
    }
    __syncthreads();

    // ---------------- Phase 2: reduce 49 partials + embed ----------------
    {
        const int k = blk * 4 + wv;          // each wave owns one (b,k), k=0..195

        // Rows s = k*3 .. k*3+2 are contiguous: 147 floats.
        const float* row = partialsT + ((size_t)batch * KC + k * 3) * BPB;
        float a0 = (lane < BPB) ? row[lane]           : 0.0f;
        float a1 = (lane < BPB) ? row[BPB + lane]     : 0.0f;
        float a2 = (lane < BPB) ? row[2 * BPB + lane] : 0.0f;

        #pragma unroll
        for (int off = 32; off > 0; off >>= 1) {
            a0 += __shfl_xor(a0, off, 64);
            a1 += __shfl_xor(a1, off, 64);
            a2 += __shfl_xor(a2, off, 64);
        }
        const float p0 = a0 * (1.0f / (float)HW);
        const float p1 = a1 * (1.0f / (float)HW);
        const float p2 = a2 * (1.0f / (float)HW);

        const float4* W4 = (const float4*)Wm;    // row c starts at c*192 float4s
        const float4* B4 = (const float4*)bias;
        float4* O4 = (float4*)out + ((size_t)batch * Kn + k) * (En / 4);

        #pragma unroll
        for (int part = 0; part < 3; ++part) {
            const int idx = part * 64 + lane;    // coalesced across the wave
            const float4 w0 = W4[idx];
            const float4 w1 = W4[192 + idx];
            const float4 w2 = W4[384 + idx];
            const float4 bb = B4[idx];
            float4 r;
            r.x = p0 * w0.x + p1 * w1.x + p2 * w2.x + bb.x;
            r.y = p0 * w0.y + p1 * w1.y + p2 * w2.y + bb.y;
            r.z = p0 * w0.z + p1 * w1.z + p2 * w2.z + bb.z;
            r.w = p0 * w0.w + p1 * w1.w + p2 * w2.w + bb.w;
            O4[idx] = r;
        }
    }
}

extern "C" void kernel_launch(void* const* d_in, const int* in_sizes, int n_in,
                              void* d_out, int out_size, void* d_ws, size_t ws_size,
                              hipStream_t stream) {
    const float* img  = (const float*)d_in[0];  // (4,3,224,224) fp32
    const int*   seg  = (const int*)  d_in[1];  // (4,224,224) int32
    const float* Wm   = (const float*)d_in[2];  // (3,768) fp32
    const float* bias = (const float*)d_in[3];  // (768,) fp32
    float* out       = (float*)d_out;           // (4,196,768) fp32
    float* partialsT = (float*)d_ws;            // (B,KC,BPB) = 461 KB, fully overwritten

    fused_seg_embed<<<NPOOL, 256, 0, stream>>>(img, seg, Wm, bias, out, partialsT);
}

// Round 4
// 67.379 us; speedup vs baseline: 1.6176x; 1.2492x over previous
//
#include <hip/hip_runtime.h>

// Problem constants (match reference file)
#define Bn  4
#define Cn  3
#define Hn  224
#define Wn  224
#define Kn  196
#define En  768
#define HW  (Hn * Wn)            // 50176 pixels per (b,c) plane
#define BPB 49                   // pooling blocks per batch
#define NPOOL (Bn * BPB)         // 196 pooling blocks total
#define KC  (Kn * Cn)            // 588 histogram slots

// Session-verified best structure (67.0 us). Two regular graph-captured
// launches. Fusion alternatives both measured WORSE on this harness:
//   - hipLaunchCooperativeKernel: +42 us host/dispatch overhead
//   - single launch + per-batch software barrier (device-scope fences on
//     non-coherent XCD L2s): +17 us
// The timed window is dominated by the harness's 40 us workspace re-poison
// fill (83% HBM peak) + ~23 us of restore dispatches; these two kernels are
// ~3-4 us combined.

// Kernel 1: per-block segmented partial sums.
// - 1024 contiguous pixels per block (256 thr x 4 px, int4/float4 loads)
// - DUAL privatized LDS histograms (waves 0-1 -> acc[0], waves 2-3 -> acc[1])
//   to halve cross-wave same-address atomic serialization.
// - TRANSPOSED store: partials_T[b][s][j] (s = k*3+c, j = pool block).
//   Scattered 4B stores are fire-and-forget through L2; this buys kernel 2
//   fully contiguous reads of its 147-float reduction row.
// Every byte of partials_T is overwritten -> no workspace pre-zeroing.
__global__ __launch_bounds__(256) void seg_pool_partial(
    const float* __restrict__ img,        // (B,C,H,W)
    const int*   __restrict__ seg,        // (B,H,W)
    float*       __restrict__ partialsT)  // (B, KC, BPB)
{
    __shared__ float acc[2][KC];
    const int tid = threadIdx.x;
    for (int i = tid; i < 2 * KC; i += 256) ((float*)acc)[i] = 0.0f;
    __syncthreads();

    const int batch = blockIdx.x / BPB;
    const int blk   = blockIdx.x % BPB;
    const int p4    = blk * 256 + tid;   // float4 index within a plane
    const int h     = tid >> 7;          // 0 for waves 0-1, 1 for waves 2-3

    const int4*   seg4 = (const int4*)(seg + (size_t)batch * HW);
    const float4* im   = (const float4*)(img + (size_t)batch * Cn * HW);

    const int4   s  = seg4[p4];
    const float4 v0 = im[p4];                 // c = 0 plane
    const float4 v1 = im[HW / 4 + p4];        // c = 1 plane
    const float4 v2 = im[2 * (HW / 4) + p4];  // c = 2 plane

    float* a = acc[h];
    atomicAdd(&a[s.x * 3 + 0], v0.x);
    atomicAdd(&a[s.x * 3 + 1], v1.x);
    atomicAdd(&a[s.x * 3 + 2], v2.x);
    atomicAdd(&a[s.y * 3 + 0], v0.y);
    atomicAdd(&a[s.y * 3 + 1], v1.y);
    atomicAdd(&a[s.y * 3 + 2], v2.y);
    atomicAdd(&a[s.z * 3 + 0], v0.z);
    atomicAdd(&a[s.z * 3 + 1], v1.z);
    atomicAdd(&a[s.z * 3 + 2], v2.z);
    atomicAdd(&a[s.w * 3 + 0], v0.w);
    atomicAdd(&a[s.w * 3 + 1], v1.w);
    atomicAdd(&a[s.w * 3 + 2], v2.w);
    __syncthreads();

    // Transposed store: column j=blk of the (KC x BPB) matrix for this batch.
    float* dst = partialsT + (size_t)batch * KC * BPB + blk;
    for (int sidx = tid; sidx < KC; sidx += 256)
        dst[(size_t)sidx * BPB] = acc[0][sidx] + acc[1][sidx];
}

// Kernel 2: 196 blocks x 256 threads; each WAVE owns one (b,k).
// No LDS, no __syncthreads. Contiguous 147-float row load, 6-step
// __shfl_xor butterfly (all 64 lanes), then coalesced float4 GEMV row:
// out[b,k,e] = (1/HW) * sum_c pooled_c * W[c,e] + bias[e].
__global__ __launch_bounds__(256) void embed_kernel(
    const float* __restrict__ partialsT,  // (B, KC, BPB)
    const float* __restrict__ Wm,         // (C,E)
    const float* __restrict__ bias,       // (E,)
    float*       __restrict__ out)        // (B,K,E)
{
    const int tid  = threadIdx.x;
    const int lane = tid & 63;
    const int wv   = tid >> 6;                    // 4 waves -> 4 k's per block
    const int b    = blockIdx.x / BPB;
    const int k    = (blockIdx.x % BPB) * 4 + wv; // covers k = 0..195

    // Rows s = k*3 .. k*3+2 are contiguous: 147 floats.
    const float* row = partialsT + ((size_t)b * KC + k * 3) * BPB;
    float a0 = (lane < BPB) ? row[lane]           : 0.0f;
    float a1 = (lane < BPB) ? row[BPB + lane]     : 0.0f;
    float a2 = (lane < BPB) ? row[2 * BPB + lane] : 0.0f;

    #pragma unroll
    for (int off = 32; off > 0; off >>= 1) {
        a0 += __shfl_xor(a0, off, 64);
        a1 += __shfl_xor(a1, off, 64);
        a2 += __shfl_xor(a2, off, 64);
    }
    const float p0 = a0 * (1.0f / (float)HW);
    const float p1 = a1 * (1.0f / (float)HW);
    const float p2 = a2 * (1.0f / (float)HW);

    const float4* W4 = (const float4*)Wm;    // row c starts at c*192 float4s
    const float4* B4 = (const float4*)bias;
    float4* O4 = (float4*)out + ((size_t)b * Kn + k) * (En / 4);

    #pragma unroll
    for (int part = 0; part < 3; ++part) {
        const int idx = part * 64 + lane;    // coalesced across the wave
        const float4 w0 = W4[idx];
        const float4 w1 = W4[192 + idx];
        const float4 w2 = W4[384 + idx];
        const float4 bb = B4[idx];
        float4 r;
        r.x = p0 * w0.x + p1 * w1.x + p2 * w2.x + bb.x;
        r.y = p0 * w0.y + p1 * w1.y + p2 * w2.y + bb.y;
        r.z = p0 * w0.z + p1 * w1.z + p2 * w2.z + bb.z;
        r.w = p0 * w0.w + p1 * w1.w + p2 * w2.w + bb.w;
        O4[idx] = r;
    }
}

extern "C" void kernel_launch(void* const* d_in, const int* in_sizes, int n_in,
                              void* d_out, int out_size, void* d_ws, size_t ws_size,
                              hipStream_t stream) {
    const float* img  = (const float*)d_in[0];  // (4,3,224,224) fp32
    const int*   seg  = (const int*)  d_in[1];  // (4,224,224) int32
    const float* Wm   = (const float*)d_in[2];  // (3,768) fp32
    const float* bias = (const float*)d_in[3];  // (768,) fp32
    float* out       = (float*)d_out;           // (4,196,768) fp32
    float* partialsT = (float*)d_ws;            // (B,KC,BPB) = 461 KB, fully overwritten

    seg_pool_partial<<<NPOOL, 256, 0, stream>>>(img, seg, partialsT);
    embed_kernel<<<NPOOL, 256, 0, stream>>>(partialsT, Wm, bias, out);
}